// Round 14
// baseline (177.847 us; speedup 1.0000x reference)
//
#include <hip/hip_runtime.h>

#define IN_CH 128
#define OUT_CH 32
#define HEADS 8
#define HC 256            // HEADS*OUT_CH
#define NEG_SLOPE 0.2f

typedef __attribute__((ext_vector_type(8))) short short8;   // 8 bf16 = 4 VGPR
typedef __attribute__((ext_vector_type(4))) float f32x4;

// bf16 helpers (RNE)
__device__ __forceinline__ float bflo(unsigned u) { return __uint_as_float(u << 16); }
__device__ __forceinline__ float bfhi(unsigned u) { return __uint_as_float(u & 0xffff0000u); }
__device__ __forceinline__ float bf2f(unsigned short u) { return __uint_as_float(((unsigned)u) << 16); }
__device__ __forceinline__ unsigned short f2bf(float f) {
    unsigned u = __float_as_uint(f);
    u = (u + 0x7fffu + ((u >> 16) & 1u)) >> 16;
    return (unsigned short)u;
}

// ---------------- Fused prep ∥ hist ----------------
__global__ __launch_bounds__(256)
void gat_prep_hist(const float* __restrict__ W, unsigned short* __restrict__ Wt,
                   const float* __restrict__ attS, const float* __restrict__ attD,
                   unsigned short* __restrict__ Blt,
                   const int* __restrict__ dst, int* __restrict__ counts,
                   int* __restrict__ rank, int E)
{
    const int tid = threadIdx.x;
    if (blockIdx.x < 128) {
        const int idx = blockIdx.x * 256 + tid;   // 0..32767
        const int k = idx >> 8;
        const int col = idx & 255;
        Wt[col * IN_CH + k] = f2bf(W[idx]);
        if (idx < 16 * HC) {   // Blt[j][k]: j<8 -> attS head j; j>=8 -> attD head j-8
            const int j = idx >> 8;
            const int kk = idx & 255;
            float v = 0.f;
            if (j < 8)  v = ((kk >> 5) == j)       ? attS[kk] : 0.f;
            else        v = ((kk >> 5) == (j - 8)) ? attD[kk] : 0.f;
            Blt[j * HC + kk] = f2bf(v);
        }
        return;
    }
    int i = ((blockIdx.x - 128) * 256 + tid) * 8;
    if (i + 7 < E) {
        const int4 d0 = *(const int4*)&dst[i];
        const int4 d1 = *(const int4*)&dst[i + 4];
        int4 r0, r1;
        r0.x = atomicAdd(&counts[d0.x], 1);
        r0.y = atomicAdd(&counts[d0.y], 1);
        r0.z = atomicAdd(&counts[d0.z], 1);
        r0.w = atomicAdd(&counts[d0.w], 1);
        r1.x = atomicAdd(&counts[d1.x], 1);
        r1.y = atomicAdd(&counts[d1.y], 1);
        r1.z = atomicAdd(&counts[d1.z], 1);
        r1.w = atomicAdd(&counts[d1.w], 1);
        *(int4*)&rank[i] = r0;
        *(int4*)&rank[i + 4] = r1;
    } else {
        for (; i < E; ++i) rank[i] = atomicAdd(&counts[dst[i]], 1);
    }
}

// ---------------- MFMA projection (unchanged from r13) ----------------
__global__ __launch_bounds__(256)
void gat_proj_mfma(const float* __restrict__ x, const unsigned short* __restrict__ Wt,
                   const unsigned short* __restrict__ Blt,
                   unsigned short* __restrict__ h, float* __restrict__ aSD, int N)
{
    __shared__ unsigned short lbuf[32 * 264];
    __shared__ float red[4][2][16][16];

    const int tid = threadIdx.x;
    const int lane = tid & 63;
    const int w = tid >> 6;
    const int row0 = blockIdx.x * 32;

#pragma unroll
    for (int u = 0; u < 2; ++u) {
        const int unit = tid + u * 256;
        const int srow = unit >> 4;
        const int sseg = unit & 15;
        const int grow = row0 + srow;
        float4 v0 = make_float4(0.f, 0.f, 0.f, 0.f), v1 = v0;
        if (grow < N) {
            const float* xp = x + (size_t)grow * IN_CH + sseg * 8;
            v0 = *(const float4*)xp;
            v1 = *(const float4*)(xp + 4);
        }
        short8 pk;
        pk[0] = (short)f2bf(v0.x); pk[1] = (short)f2bf(v0.y);
        pk[2] = (short)f2bf(v0.z); pk[3] = (short)f2bf(v0.w);
        pk[4] = (short)f2bf(v1.x); pk[5] = (short)f2bf(v1.y);
        pk[6] = (short)f2bf(v1.z); pk[7] = (short)f2bf(v1.w);
        *(short8*)&lbuf[srow * 136 + sseg * 8] = pk;
    }
    __syncthreads();

    const unsigned short* wp = Wt + (size_t)(w * 64 + (lane & 15)) * IN_CH
                                  + ((lane >> 4) << 3);

    f32x4 acc[2][4];
#pragma unroll
    for (int m = 0; m < 2; ++m)
#pragma unroll
        for (int i = 0; i < 4; ++i) acc[m][i] = (f32x4){0.f, 0.f, 0.f, 0.f};

#pragma unroll
    for (int ks = 0; ks < 4; ++ks) {
        short8 bfr[4];
#pragma unroll
        for (int i = 0; i < 4; ++i)
            bfr[i] = *(const short8*)(wp + i * 16 * IN_CH + ks * 32);
#pragma unroll
        for (int m = 0; m < 2; ++m) {
            const short8 a = *(const short8*)&lbuf[((lane & 15) + m * 16) * 136
                                                   + ks * 32 + ((lane >> 4) << 3)];
#pragma unroll
            for (int i = 0; i < 4; ++i)
                acc[m][i] = __builtin_amdgcn_mfma_f32_16x16x32_bf16(a, bfr[i], acc[m][i], 0, 0, 0);
        }
    }

    __syncthreads();
    const int rbase = (lane >> 4) << 2;
#pragma unroll
    for (int i = 0; i < 4; ++i) {
        const int col = w * 64 + i * 16 + (lane & 15);
#pragma unroll
        for (int m = 0; m < 2; ++m)
#pragma unroll
            for (int r = 0; r < 4; ++r)
                lbuf[(m * 16 + rbase + r) * 264 + col] = f2bf(acc[m][i][r]);
    }
    __syncthreads();

#pragma unroll
    for (int u = 0; u < 4; ++u) {
        const int unit = u * 256 + tid;
        const int srow = unit >> 5;
        const int sseg = unit & 31;
        const int grow = row0 + srow;
        if (grow < N)
            *(short8*)(h + (size_t)grow * HC + sseg * 8) =
                *(const short8*)&lbuf[srow * 264 + sseg * 8];
    }

    // logit MFMA: wave w covers channels [w*64, w*64+64)
    f32x4 cl[2] = {{0.f,0.f,0.f,0.f},{0.f,0.f,0.f,0.f}};
#pragma unroll
    for (int kl = 0; kl < 2; ++kl) {
        const int ks = w * 2 + kl;
        const short8 b = *(const short8*)(Blt + (lane & 15) * HC + ks * 32 + ((lane >> 4) << 3));
#pragma unroll
        for (int m = 0; m < 2; ++m) {
            const short8 a = *(const short8*)&lbuf[((lane & 15) + m * 16) * 264
                                                   + ks * 32 + ((lane >> 4) << 3)];
            cl[m] = __builtin_amdgcn_mfma_f32_16x16x32_bf16(a, b, cl[m], 0, 0, 0);
        }
    }
#pragma unroll
    for (int m = 0; m < 2; ++m)
#pragma unroll
        for (int r = 0; r < 4; ++r)
            red[w][m][rbase + r][lane & 15] = cl[m][r];
    __syncthreads();

#pragma unroll
    for (int u = 0; u < 2; ++u) {
        const int o = u * 256 + tid;
        const int m = o >> 8;
        const int row = (o >> 4) & 15;
        const int j = o & 15;
        const float s = red[0][m][row][j] + red[1][m][row][j]
                      + red[2][m][row][j] + red[3][m][row][j];
        const int grow = row0 + m * 16 + row;
        if (grow < N) aSD[grow * 16 + j] = s;
    }
}

// phase 1: per-1024-chunk sums of PADDED counts (pad to multiple of 8)
__global__ __launch_bounds__(256)
void gat_scan1(const int* __restrict__ counts, int* __restrict__ bsum, int n)
{
    __shared__ int ws[4];
    const int t = threadIdx.x;
    const int lane = t & 63;
    const int wid = t >> 6;
    const int idx = blockIdx.x * 1024 + t * 4;
    int4 v = {0, 0, 0, 0};
    if (idx + 3 < n) v = *(const int4*)&counts[idx];
    else {
        if (idx < n)     v.x = counts[idx];
        if (idx + 1 < n) v.y = counts[idx + 1];
        if (idx + 2 < n) v.z = counts[idx + 2];
    }
    const int px = (v.x + 7) & ~7, py = (v.y + 7) & ~7;
    const int pz = (v.z + 7) & ~7, pw = (v.w + 7) & ~7;
    int s4 = px + py + pz + pw;
#pragma unroll
    for (int off = 1; off < 64; off <<= 1) s4 += __shfl_xor(s4, off, 64);
    if (lane == 0) ws[wid] = s4;
    __syncthreads();
    if (t == 0) bsum[blockIdx.x] = ws[0] + ws[1] + ws[2] + ws[3];
}

// phase 2: padded scan -> offsets; fill pad slots (ssrc=node, ealpha=0)
// and 8 slack entries past the padded total for unconditional prefetch.
__global__ __launch_bounds__(256)
void gat_scan3(const int* __restrict__ counts, const int* __restrict__ bsum,
               int* __restrict__ offsets, int* __restrict__ ssrc,
               unsigned short* __restrict__ ealpha, int n, int nb)
{
    __shared__ int wsums[4];
    __shared__ int bbase_s;
    const int t = threadIdx.x;
    const int lane = t & 63;
    const int wid = t >> 6;

    if (t < 64) {   // wave 0: exclusive prefix of bsum at index blockIdx.x
        const int v = (t < nb) ? bsum[t] : 0;
        int inc = v;
#pragma unroll
        for (int off = 1; off < 64; off <<= 1) {
            const int y = __shfl_up(inc, off, 64);
            if (t >= off) inc += y;
        }
        const int myv   = __shfl(v, blockIdx.x, 64);
        const int myinc = __shfl(inc, blockIdx.x, 64);
        if (t == 0) bbase_s = myinc - myv;
        if (blockIdx.x == 0 && t == 63) {
            offsets[n] = inc;                 // padded grand total
            // slack entries for branch-free prefetch
            for (int k = 0; k < 8; ++k) {
                ssrc[inc + k] = 0;
                *(int4*)(ealpha + (size_t)(inc + k) * HEADS) = (int4){0, 0, 0, 0};
            }
        }
    }

    const int idx = blockIdx.x * 1024 + t * 4;
    int4 v = {0, 0, 0, 0};
    if (idx + 3 < n) v = *(const int4*)&counts[idx];
    else {
        if (idx < n)     v.x = counts[idx];
        if (idx + 1 < n) v.y = counts[idx + 1];
        if (idx + 2 < n) v.z = counts[idx + 2];
    }
    int4 p;
    p.x = (v.x + 7) & ~7; p.y = (v.y + 7) & ~7;
    p.z = (v.z + 7) & ~7; p.w = (v.w + 7) & ~7;
    const int s4 = p.x + p.y + p.z + p.w;
    int inc = s4;
#pragma unroll
    for (int off = 1; off < 64; off <<= 1) {
        const int y = __shfl_up(inc, off, 64);
        if (lane >= off) inc += y;
    }
    if (lane == 63) wsums[wid] = inc;
    __syncthreads();
    int wbase = 0;
    for (int i = 0; i < wid; ++i) wbase += wsums[i];
    const int base = bbase_s + wbase + (inc - s4);
    int4 o;
    o.x = base;
    o.y = base + p.x;
    o.z = o.y + p.y;
    o.w = o.z + p.z;
    if (idx + 3 < n) {
        *(int4*)&offsets[idx] = o;
    } else {
        if (idx < n)     offsets[idx] = o.x;
        if (idx + 1 < n) offsets[idx + 1] = o.y;
        if (idx + 2 < n) offsets[idx + 2] = o.z;
    }
    // fill pad slots for this thread's 4 nodes
    const int ob[4] = { o.x, o.y, o.z, o.w };
    const int vb[4] = { v.x, v.y, v.z, v.w };
    const int pb[4] = { p.x, p.y, p.z, p.w };
#pragma unroll
    for (int c = 0; c < 4; ++c) {
        const int node = idx + c;
        if (node < n) {
            for (int k = vb[c]; k < pb[c]; ++k) {
                const int pos = ob[c] + k;
                ssrc[pos] = node;
                *(int4*)(ealpha + (size_t)pos * HEADS) = (int4){0, 0, 0, 0};
            }
        }
    }
}

// scatter WITHOUT atomics: pos = offsets[dst] + rank[e].
__global__ __launch_bounds__(256)
void gat_scatter(const int* __restrict__ src, const int* __restrict__ dst,
                 const int* __restrict__ rank, const int* __restrict__ offsets,
                 int* __restrict__ ssrc, unsigned short* __restrict__ ealpha,
                 const float* __restrict__ aSD, int E)
{
    const int e = blockIdx.x * 256 + threadIdx.x;
    if (e >= E) return;
    const int s = src[e];
    const int d = dst[e];
    const int pos = offsets[d] + rank[e];
    ssrc[pos] = s;
    const float4 s0 = *(const float4*)(aSD + (size_t)s * 16);
    const float4 s1 = *(const float4*)(aSD + (size_t)s * 16 + 4);
    const float4 d0 = *(const float4*)(aSD + (size_t)d * 16 + 8);
    const float4 d1 = *(const float4*)(aSD + (size_t)d * 16 + 12);
    float lg[8] = { s0.x + d0.x, s0.y + d0.y, s0.z + d0.z, s0.w + d0.w,
                    s1.x + d1.x, s1.y + d1.y, s1.z + d1.z, s1.w + d1.w };
    short8 al;
#pragma unroll
    for (int k = 0; k < 8; ++k) {
        const float v = lg[k] > 0.f ? lg[k] : NEG_SLOPE * lg[k];
        al[k] = (short)f2bf(__expf(v));
    }
    *(short8*)(ealpha + (size_t)pos * HEADS) = al;
}

// ---------------- Per-node aggregation: padded, branch-free inner loop ----------------
__global__ __launch_bounds__(256)
void gat_agg(const unsigned short* __restrict__ h, const float* __restrict__ aSD,
             const int* __restrict__ offsets, const int* __restrict__ ssrc,
             const unsigned short* __restrict__ ealpha,
             const float* __restrict__ bias, float* __restrict__ out, int N)
{
    const int t = threadIdx.x;
    const int lane = t & 63;
    const int node = blockIdx.x * 4 + (t >> 6);
    if (node >= N) return;

    const int half = lane >> 5;
    const int hl = lane & 31;
    const int head = hl >> 2;
    const int ch = head * 32 + (hl & 3) * 8;

    float sum;
    float acc[8];
    {
        float lg0 = aSD[(size_t)node * 16 + head] + aSD[(size_t)node * 16 + 8 + head];
        lg0 = (lg0 > 0.f) ? lg0 : NEG_SLOPE * lg0;
        const float w0 = half ? 0.f : __expf(lg0);
        sum = w0;
        const uint4 hv = *(const uint4*)(h + (size_t)node * HC + ch);
        acc[0] = w0 * bflo(hv.x); acc[1] = w0 * bfhi(hv.x);
        acc[2] = w0 * bflo(hv.y); acc[3] = w0 * bfhi(hv.y);
        acc[4] = w0 * bflo(hv.z); acc[5] = w0 * bfhi(hv.z);
        acc[6] = w0 * bflo(hv.w); acc[7] = w0 * bfhi(hv.w);
    }

    const int beg = offsets[node];
    const int end = offsets[node + 1];   // padded to multiple of 8

    if (beg < end) {   // wave-uniform
        int sE[4]; float aE[4];
        const int e0 = beg + half * 4;
#pragma unroll
        for (int j = 0; j < 4; ++j) {
            sE[j] = ssrc[e0 + j];
            aE[j] = bf2f(ealpha[(size_t)(e0 + j) * HEADS + head]);
        }
        for (int base = beg; base < end; base += 8) {
            const int np = base + 8 + half * 4;   // slack-safe unconditional prefetch
            int tS[4]; float tA[4];
#pragma unroll
            for (int j = 0; j < 4; ++j) {
                tS[j] = ssrc[np + j];
                tA[j] = bf2f(ealpha[(size_t)(np + j) * HEADS + head]);
            }
            uint4 v[4];
#pragma unroll
            for (int j = 0; j < 4; ++j)
                v[j] = *(const uint4*)(h + (size_t)sE[j] * HC + ch);
#pragma unroll
            for (int j = 0; j < 4; ++j) {
                const float a = aE[j];
                sum += a;
                acc[0] = fmaf(a, bflo(v[j].x), acc[0]);
                acc[1] = fmaf(a, bfhi(v[j].x), acc[1]);
                acc[2] = fmaf(a, bflo(v[j].y), acc[2]);
                acc[3] = fmaf(a, bfhi(v[j].y), acc[3]);
                acc[4] = fmaf(a, bflo(v[j].z), acc[4]);
                acc[5] = fmaf(a, bfhi(v[j].z), acc[5]);
                acc[6] = fmaf(a, bflo(v[j].w), acc[6]);
                acc[7] = fmaf(a, bfhi(v[j].w), acc[7]);
            }
#pragma unroll
            for (int j = 0; j < 4; ++j) { sE[j] = tS[j]; aE[j] = tA[j]; }
        }
    }

#pragma unroll
    for (int j = 0; j < 8; ++j) acc[j] += __shfl_xor(acc[j], 32, 64);
    sum += __shfl_xor(sum, 32, 64);

    const float inv = 1.f / (sum + 1e-16f);
    const int cbase = ch + half * 4;
    const int j0 = half * 4;
    const float4 bv = *(const float4*)(bias + cbase);
    float4 o;
    o.x = fmaxf(fmaf(acc[j0 + 0], inv, bv.x), 0.f);
    o.y = fmaxf(fmaf(acc[j0 + 1], inv, bv.y), 0.f);
    o.z = fmaxf(fmaf(acc[j0 + 2], inv, bv.z), 0.f);
    o.w = fmaxf(fmaf(acc[j0 + 3], inv, bv.w), 0.f);
    *(float4*)(out + (size_t)node * HC + cbase) = o;
}

extern "C" void kernel_launch(void* const* d_in, const int* in_sizes, int n_in,
                              void* d_out, int out_size, void* d_ws, size_t ws_size,
                              hipStream_t stream)
{
    const float* x    = (const float*)d_in[0];
    const int*   ei   = (const int*)d_in[1];
    const float* W    = (const float*)d_in[2];
    const float* attS = (const float*)d_in[3];
    const float* attD = (const float*)d_in[4];
    const float* bias = (const float*)d_in[5];
    float* out = (float*)d_out;

    const int N = in_sizes[0] / IN_CH;
    const int E = in_sizes[1] / 2;
    const int* esrc = ei;
    const int* edst = ei + E;

    const int EPMAX = E + 8 * N + 16;                 // padded-edge capacity

    unsigned short* h = (unsigned short*)d_ws;        // N*256 bf16
    float* aSD = (float*)(h + (size_t)N * HC);        // N*16
    int* counts  = (int*)(aSD + (size_t)N * 16);      // N
    int* offsets = counts + N;                        // N+1 (padded to N+4)
    int* rank    = offsets + (N + 4);                 // E
    int* ssrc    = rank + E;                          // EPMAX
    int* bsum    = ssrc + EPMAX;                      // <=64
    unsigned short* Wt = (unsigned short*)(bsum + 64);// 256*128 bf16
    unsigned short* Blt = Wt + IN_CH * HC;            // 16*256 bf16
    unsigned short* ealpha = Blt + 16 * HC;           // EPMAX*8 bf16

    const int nb = (N + 1023) / 1024;                 // 49 (must be <=64)
    const int histBlocks = (E / 8 + 255) / 256;       // 391

    hipMemsetAsync(counts, 0, (size_t)N * sizeof(int), stream);
    gat_prep_hist<<<128 + histBlocks, 256, 0, stream>>>(
        W, Wt, attS, attD, Blt, edst, counts, rank, E);
    gat_proj_mfma<<<(N + 31) / 32, 256, 0, stream>>>(x, Wt, Blt, h, aSD, N);
    gat_scan1<<<nb, 256, 0, stream>>>(counts, bsum, N);
    gat_scan3<<<nb, 256, 0, stream>>>(counts, bsum, offsets, ssrc, ealpha, N, nb);
    gat_scatter<<<(E + 255) / 256, 256, 0, stream>>>(esrc, edst, rank, offsets, ssrc, ealpha, aSD, E);
    gat_agg<<<(N + 3) / 4, 256, 0, stream>>>(h, aSD, offsets, ssrc, ealpha, bias, out, N);
}

// Round 15
// 173.035 us; speedup vs baseline: 1.0278x; 1.0278x over previous
//
#include <hip/hip_runtime.h>

#define IN_CH 128
#define OUT_CH 32
#define HEADS 8
#define HC 256            // HEADS*OUT_CH
#define NEG_SLOPE 0.2f

typedef __attribute__((ext_vector_type(8))) short short8;   // 8 bf16 = 4 VGPR
typedef __attribute__((ext_vector_type(4))) float f32x4;

// bf16 helpers (RNE)
__device__ __forceinline__ float bflo(unsigned u) { return __uint_as_float(u << 16); }
__device__ __forceinline__ float bfhi(unsigned u) { return __uint_as_float(u & 0xffff0000u); }
__device__ __forceinline__ float bf2f(unsigned short u) { return __uint_as_float(((unsigned)u) << 16); }
__device__ __forceinline__ unsigned short f2bf(float f) {
    unsigned u = __float_as_uint(f);
    u = (u + 0x7fffu + ((u >> 16) & 1u)) >> 16;
    return (unsigned short)u;
}

// ---------------- Fused prep ∥ hist ----------------
// Blocks [0,128): Wt transpose->bf16 + Blt (masked attention B-matrix).
// Blocks [128,...): histogram with captured rank. Both paths tiny VGPR, no LDS.
__global__ __launch_bounds__(256)
void gat_prep_hist(const float* __restrict__ W, unsigned short* __restrict__ Wt,
                   const float* __restrict__ attS, const float* __restrict__ attD,
                   unsigned short* __restrict__ Blt,
                   const int* __restrict__ dst, int* __restrict__ counts,
                   int* __restrict__ rank, int E)
{
    const int tid = threadIdx.x;
    if (blockIdx.x < 128) {
        const int idx = blockIdx.x * 256 + tid;   // 0..32767
        const int k = idx >> 8;
        const int col = idx & 255;
        Wt[col * IN_CH + k] = f2bf(W[idx]);
        if (idx < 16 * HC) {   // Blt[j][k]: j<8 -> attS head j; j>=8 -> attD head j-8
            const int j = idx >> 8;
            const int kk = idx & 255;
            float v = 0.f;
            if (j < 8)  v = ((kk >> 5) == j)       ? attS[kk] : 0.f;
            else        v = ((kk >> 5) == (j - 8)) ? attD[kk] : 0.f;
            Blt[j * HC + kk] = f2bf(v);
        }
        return;
    }
    // hist path
    int i = ((blockIdx.x - 128) * 256 + tid) * 8;
    if (i + 7 < E) {
        const int4 d0 = *(const int4*)&dst[i];
        const int4 d1 = *(const int4*)&dst[i + 4];
        int4 r0, r1;
        r0.x = atomicAdd(&counts[d0.x], 1);
        r0.y = atomicAdd(&counts[d0.y], 1);
        r0.z = atomicAdd(&counts[d0.z], 1);
        r0.w = atomicAdd(&counts[d0.w], 1);
        r1.x = atomicAdd(&counts[d1.x], 1);
        r1.y = atomicAdd(&counts[d1.y], 1);
        r1.z = atomicAdd(&counts[d1.z], 1);
        r1.w = atomicAdd(&counts[d1.w], 1);
        *(int4*)&rank[i] = r0;
        *(int4*)&rank[i + 4] = r1;
    } else {
        for (; i < E; ++i) rank[i] = atomicAdd(&counts[dst[i]], 1);
    }
}

// ---------------- MFMA projection: h = x@W (bf16) + MFMA-based logits ----------------
// 32 rows x 256 cols per block (4 waves). Logits computed as a second MFMA
// (h @ Blt^T) from the transposed LDS buffer — no shuffle reduction.
// aSD[node][16]: j<8 = a_src[head j], j>=8 = a_dst[head j-8].
__global__ __launch_bounds__(256)
void gat_proj_mfma(const float* __restrict__ x, const unsigned short* __restrict__ Wt,
                   const unsigned short* __restrict__ Blt,
                   unsigned short* __restrict__ h, float* __restrict__ aSD, int N)
{
    // staging view: stride 136 (32x136); transpose view: stride 264
    __shared__ unsigned short lbuf[32 * 264];
    __shared__ float red[4][2][16][16];   // [wave][m][row][j]

    const int tid = threadIdx.x;
    const int lane = tid & 63;
    const int w = tid >> 6;
    const int row0 = blockIdx.x * 32;

    // stage 32x128 x-tile -> LDS bf16 (vectorized ds_write_b128)
#pragma unroll
    for (int u = 0; u < 2; ++u) {
        const int unit = tid + u * 256;
        const int srow = unit >> 4;
        const int sseg = unit & 15;
        const int grow = row0 + srow;
        float4 v0 = make_float4(0.f, 0.f, 0.f, 0.f), v1 = v0;
        if (grow < N) {
            const float* xp = x + (size_t)grow * IN_CH + sseg * 8;
            v0 = *(const float4*)xp;
            v1 = *(const float4*)(xp + 4);
        }
        short8 pk;
        pk[0] = (short)f2bf(v0.x); pk[1] = (short)f2bf(v0.y);
        pk[2] = (short)f2bf(v0.z); pk[3] = (short)f2bf(v0.w);
        pk[4] = (short)f2bf(v1.x); pk[5] = (short)f2bf(v1.y);
        pk[6] = (short)f2bf(v1.z); pk[7] = (short)f2bf(v1.w);
        *(short8*)&lbuf[srow * 136 + sseg * 8] = pk;
    }
    __syncthreads();

    const unsigned short* wp = Wt + (size_t)(w * 64 + (lane & 15)) * IN_CH
                                  + ((lane >> 4) << 3);

    f32x4 acc[2][4];
#pragma unroll
    for (int m = 0; m < 2; ++m)
#pragma unroll
        for (int i = 0; i < 4; ++i) acc[m][i] = (f32x4){0.f, 0.f, 0.f, 0.f};

#pragma unroll
    for (int ks = 0; ks < 4; ++ks) {
        short8 bfr[4];
#pragma unroll
        for (int i = 0; i < 4; ++i)
            bfr[i] = *(const short8*)(wp + i * 16 * IN_CH + ks * 32);
#pragma unroll
        for (int m = 0; m < 2; ++m) {
            const short8 a = *(const short8*)&lbuf[((lane & 15) + m * 16) * 136
                                                   + ks * 32 + ((lane >> 4) << 3)];
#pragma unroll
            for (int i = 0; i < 4; ++i)
                acc[m][i] = __builtin_amdgcn_mfma_f32_16x16x32_bf16(a, bfr[i], acc[m][i], 0, 0, 0);
        }
    }

    // transpose acc through LDS (stride 264; C/D map col=lane&15, row=(lane>>4)*4+reg)
    __syncthreads();   // all MFMA reads of lbuf done
    const int rbase = (lane >> 4) << 2;
#pragma unroll
    for (int i = 0; i < 4; ++i) {
        const int col = w * 64 + i * 16 + (lane & 15);
#pragma unroll
        for (int m = 0; m < 2; ++m)
#pragma unroll
            for (int r = 0; r < 4; ++r)
                lbuf[(m * 16 + rbase + r) * 264 + col] = f2bf(acc[m][i][r]);
    }
    __syncthreads();

    // coalesced h store: 16B/lane (reads lbuf, no writes)
#pragma unroll
    for (int u = 0; u < 4; ++u) {
        const int unit = u * 256 + tid;      // 0..1023
        const int srow = unit >> 5;          // 0..31
        const int sseg = unit & 31;          // 8 bf16 each
        const int grow = row0 + srow;
        if (grow < N)
            *(short8*)(h + (size_t)grow * HC + sseg * 8) =
                *(const short8*)&lbuf[srow * 264 + sseg * 8];
    }

    // logit MFMA: wave w covers channels [w*64, w*64+64)
    f32x4 cl[2] = {{0.f,0.f,0.f,0.f},{0.f,0.f,0.f,0.f}};
#pragma unroll
    for (int kl = 0; kl < 2; ++kl) {
        const int ks = w * 2 + kl;
        const short8 b = *(const short8*)(Blt + (lane & 15) * HC + ks * 32 + ((lane >> 4) << 3));
#pragma unroll
        for (int m = 0; m < 2; ++m) {
            const short8 a = *(const short8*)&lbuf[((lane & 15) + m * 16) * 264
                                                   + ks * 32 + ((lane >> 4) << 3)];
            cl[m] = __builtin_amdgcn_mfma_f32_16x16x32_bf16(a, b, cl[m], 0, 0, 0);
        }
    }
    // stash per-wave partials; C map: j = lane&15, row = (lane>>4)*4 + r
#pragma unroll
    for (int m = 0; m < 2; ++m)
#pragma unroll
        for (int r = 0; r < 4; ++r)
            red[w][m][rbase + r][lane & 15] = cl[m][r];
    __syncthreads();

    // reduce 4 waves + coalesced aSD write (o: j fastest -> 64B per 16 threads)
#pragma unroll
    for (int u = 0; u < 2; ++u) {
        const int o = u * 256 + tid;         // 0..511
        const int m = o >> 8;
        const int row = (o >> 4) & 15;
        const int j = o & 15;
        const float s = red[0][m][row][j] + red[1][m][row][j]
                      + red[2][m][row][j] + red[3][m][row][j];
        const int grow = row0 + m * 16 + row;
        if (grow < N) aSD[grow * 16 + j] = s;
    }
}

// phase 1: per-1024-chunk sums
__global__ __launch_bounds__(256)
void gat_scan1(const int* __restrict__ counts, int* __restrict__ bsum, int n)
{
    __shared__ int ws[4];
    const int t = threadIdx.x;
    const int lane = t & 63;
    const int wid = t >> 6;
    const int idx = blockIdx.x * 1024 + t * 4;
    int4 v = {0, 0, 0, 0};
    if (idx + 3 < n) v = *(const int4*)&counts[idx];
    else {
        if (idx < n)     v.x = counts[idx];
        if (idx + 1 < n) v.y = counts[idx + 1];
        if (idx + 2 < n) v.z = counts[idx + 2];
    }
    int s4 = v.x + v.y + v.z + v.w;
#pragma unroll
    for (int off = 1; off < 64; off <<= 1) s4 += __shfl_xor(s4, off, 64);
    if (lane == 0) ws[wid] = s4;
    __syncthreads();
    if (t == 0) bsum[blockIdx.x] = ws[0] + ws[1] + ws[2] + ws[3];
}

// phase 2: per-chunk scan; each block re-scans bsum (nb<=64) in wave 0
__global__ __launch_bounds__(256)
void gat_scan3(const int* __restrict__ counts, const int* __restrict__ bsum,
               int* __restrict__ offsets, int n, int nb, int E)
{
    __shared__ int wsums[4];
    __shared__ int bbase_s;
    const int t = threadIdx.x;
    const int lane = t & 63;
    const int wid = t >> 6;

    if (t < 64) {
        const int v = (t < nb) ? bsum[t] : 0;
        int inc = v;
#pragma unroll
        for (int off = 1; off < 64; off <<= 1) {
            const int y = __shfl_up(inc, off, 64);
            if (t >= off) inc += y;
        }
        const int myv   = __shfl(v, blockIdx.x, 64);
        const int myinc = __shfl(inc, blockIdx.x, 64);
        if (t == 0) bbase_s = myinc - myv;
    }

    const int idx = blockIdx.x * 1024 + t * 4;
    int4 v = {0, 0, 0, 0};
    if (idx + 3 < n) v = *(const int4*)&counts[idx];
    else {
        if (idx < n)     v.x = counts[idx];
        if (idx + 1 < n) v.y = counts[idx + 1];
        if (idx + 2 < n) v.z = counts[idx + 2];
    }
    const int s4 = v.x + v.y + v.z + v.w;
    int inc = s4;
#pragma unroll
    for (int off = 1; off < 64; off <<= 1) {
        const int y = __shfl_up(inc, off, 64);
        if (lane >= off) inc += y;
    }
    if (lane == 63) wsums[wid] = inc;
    __syncthreads();
    int wbase = 0;
    for (int i = 0; i < wid; ++i) wbase += wsums[i];
    const int base = bbase_s + wbase + (inc - s4);
    int4 o;
    o.x = base;
    o.y = base + v.x;
    o.z = o.y + v.y;
    o.w = o.z + v.z;
    if (idx + 3 < n) {
        *(int4*)&offsets[idx] = o;
    } else {
        if (idx < n)     offsets[idx] = o.x;
        if (idx + 1 < n) offsets[idx + 1] = o.y;
        if (idx + 2 < n) offsets[idx + 2] = o.z;
    }
    if (blockIdx.x == 0 && t == 0) offsets[n] = E;
}

// scatter WITHOUT atomics: pos = offsets[dst] + rank[e].
// ealpha[pos][head] = exp(leaky_relu(aSD[s][head] + aSD[d][8+head])) bf16
__global__ __launch_bounds__(256)
void gat_scatter(const int* __restrict__ src, const int* __restrict__ dst,
                 const int* __restrict__ rank, const int* __restrict__ offsets,
                 int* __restrict__ ssrc, unsigned short* __restrict__ ealpha,
                 const float* __restrict__ aSD, int E)
{
    const int e = blockIdx.x * 256 + threadIdx.x;
    if (e >= E) return;
    const int s = src[e];
    const int d = dst[e];
    const int pos = offsets[d] + rank[e];
    ssrc[pos] = s;
    const float4 s0 = *(const float4*)(aSD + (size_t)s * 16);
    const float4 s1 = *(const float4*)(aSD + (size_t)s * 16 + 4);
    const float4 d0 = *(const float4*)(aSD + (size_t)d * 16 + 8);
    const float4 d1 = *(const float4*)(aSD + (size_t)d * 16 + 12);
    float lg[8] = { s0.x + d0.x, s0.y + d0.y, s0.z + d0.z, s0.w + d0.w,
                    s1.x + d1.x, s1.y + d1.y, s1.z + d1.z, s1.w + d1.w };
    short8 al;
#pragma unroll
    for (int k = 0; k < 8; ++k) {
        const float v = lg[k] > 0.f ? lg[k] : NEG_SLOPE * lg[k];
        al[k] = (short)f2bf(__expf(v));
    }
    *(short8*)(ealpha + (size_t)pos * HEADS) = al;
}

// ---------------- Per-node aggregation (at throughput wall; aSD layout) ----------------
__global__ __launch_bounds__(256)
void gat_agg(const unsigned short* __restrict__ h, const float* __restrict__ aSD,
             const int* __restrict__ offsets, const int* __restrict__ ssrc,
             const unsigned short* __restrict__ ealpha,
             const float* __restrict__ bias, float* __restrict__ out, int N)
{
    const int t = threadIdx.x;
    const int lane = t & 63;
    const int node = blockIdx.x * 4 + (t >> 6);
    if (node >= N) return;

    const int half = lane >> 5;
    const int hl = lane & 31;
    const int head = hl >> 2;
    const int ch = head * 32 + (hl & 3) * 8;

    float sum;
    float acc[8];
    {
        float lg0 = aSD[(size_t)node * 16 + head] + aSD[(size_t)node * 16 + 8 + head];
        lg0 = (lg0 > 0.f) ? lg0 : NEG_SLOPE * lg0;
        const float w0 = half ? 0.f : __expf(lg0);
        sum = w0;
        const uint4 hv = *(const uint4*)(h + (size_t)node * HC + ch);
        acc[0] = w0 * bflo(hv.x); acc[1] = w0 * bfhi(hv.x);
        acc[2] = w0 * bflo(hv.y); acc[3] = w0 * bfhi(hv.y);
        acc[4] = w0 * bflo(hv.z); acc[5] = w0 * bfhi(hv.z);
        acc[6] = w0 * bflo(hv.w); acc[7] = w0 * bfhi(hv.w);
    }

    const int beg = offsets[node];
    const int end = offsets[node + 1];
    const int last = end - 1;

    int sE[4];
    float aE[4];
#pragma unroll
    for (int j = 0; j < 4; ++j) { sE[j] = node; aE[j] = 0.f; }

    if (beg < end) {
#pragma unroll
        for (int j = 0; j < 4; ++j) {
            const int e = beg + half * 4 + j;
            const int c = min(e, last);
            int s = ssrc[c];
            float a = bf2f(ealpha[(size_t)c * HEADS + head]);
            if (e > last) { s = node; a = 0.f; }
            sE[j] = s; aE[j] = a;
        }
    }

    for (int base = beg; base < end; base += 8) {
        int tS[4]; float tA[4];
#pragma unroll
        for (int j = 0; j < 4; ++j) {
            const int e = base + 8 + half * 4 + j;
            const int c = min(e, last);
            int s = ssrc[c];
            float a = bf2f(ealpha[(size_t)c * HEADS + head]);
            if (e > last) { s = node; a = 0.f; }
            tS[j] = s; tA[j] = a;
        }
        uint4 v[4];
#pragma unroll
        for (int j = 0; j < 4; ++j)
            v[j] = *(const uint4*)(h + (size_t)sE[j] * HC + ch);
#pragma unroll
        for (int j = 0; j < 4; ++j) {
            const float a = aE[j];
            sum += a;
            acc[0] = fmaf(a, bflo(v[j].x), acc[0]);
            acc[1] = fmaf(a, bfhi(v[j].x), acc[1]);
            acc[2] = fmaf(a, bflo(v[j].y), acc[2]);
            acc[3] = fmaf(a, bfhi(v[j].y), acc[3]);
            acc[4] = fmaf(a, bflo(v[j].z), acc[4]);
            acc[5] = fmaf(a, bfhi(v[j].z), acc[5]);
            acc[6] = fmaf(a, bflo(v[j].w), acc[6]);
            acc[7] = fmaf(a, bfhi(v[j].w), acc[7]);
        }
#pragma unroll
        for (int j = 0; j < 4; ++j) { sE[j] = tS[j]; aE[j] = tA[j]; }
    }

#pragma unroll
    for (int j = 0; j < 8; ++j) acc[j] += __shfl_xor(acc[j], 32, 64);
    sum += __shfl_xor(sum, 32, 64);

    const float inv = 1.f / (sum + 1e-16f);
    const int cbase = ch + half * 4;
    const int j0 = half * 4;
    const float4 bv = *(const float4*)(bias + cbase);
    float4 o;
    o.x = fmaxf(fmaf(acc[j0 + 0], inv, bv.x), 0.f);
    o.y = fmaxf(fmaf(acc[j0 + 1], inv, bv.y), 0.f);
    o.z = fmaxf(fmaf(acc[j0 + 2], inv, bv.z), 0.f);
    o.w = fmaxf(fmaf(acc[j0 + 3], inv, bv.w), 0.f);
    *(float4*)(out + (size_t)node * HC + cbase) = o;
}

extern "C" void kernel_launch(void* const* d_in, const int* in_sizes, int n_in,
                              void* d_out, int out_size, void* d_ws, size_t ws_size,
                              hipStream_t stream)
{
    const float* x    = (const float*)d_in[0];
    const int*   ei   = (const int*)d_in[1];
    const float* W    = (const float*)d_in[2];
    const float* attS = (const float*)d_in[3];
    const float* attD = (const float*)d_in[4];
    const float* bias = (const float*)d_in[5];
    float* out = (float*)d_out;

    const int N = in_sizes[0] / IN_CH;
    const int E = in_sizes[1] / 2;
    const int* esrc = ei;
    const int* edst = ei + E;

    unsigned short* h = (unsigned short*)d_ws;        // N*256 bf16
    float* aSD = (float*)(h + (size_t)N * HC);        // N*16
    int* counts  = (int*)(aSD + (size_t)N * 16);      // N
    int* offsets = counts + N;                        // N+1 (padded to N+4)
    int* rank    = offsets + (N + 4);                 // E
    int* ssrc    = rank + E;                          // E
    int* bsum    = ssrc + E;                          // <=64
    unsigned short* Wt = (unsigned short*)(bsum + 64);// 256*128 bf16
    unsigned short* Blt = Wt + IN_CH * HC;            // 16*256 bf16
    unsigned short* ealpha = Blt + 16 * HC;           // E*8 bf16

    const int nb = (N + 1023) / 1024;                 // 49 (must be <=64)
    const int histBlocks = (E / 8 + 255) / 256;       // 391

    hipMemsetAsync(counts, 0, (size_t)N * sizeof(int), stream);
    gat_prep_hist<<<128 + histBlocks, 256, 0, stream>>>(
        W, Wt, attS, attD, Blt, edst, counts, rank, E);
    gat_proj_mfma<<<(N + 31) / 32, 256, 0, stream>>>(x, Wt, Blt, h, aSD, N);
    gat_scan1<<<nb, 256, 0, stream>>>(counts, bsum, N);
    gat_scan3<<<nb, 256, 0, stream>>>(counts, bsum, offsets, N, nb, E);
    gat_scatter<<<(E + 255) / 256, 256, 0, stream>>>(esrc, edst, rank, offsets, ssrc, ealpha, aSD, E);
    gat_agg<<<(N + 3) / 4, 256, 0, stream>>>(h, aSD, offsets, ssrc, ealpha, bias, out, N);
}